// Round 11
// baseline (238.249 us; speedup 1.0000x reference)
//
#include <hip/hip_runtime.h>
#include <math.h>

#define NUM_NODES 2000000
#define NUM_FLOPS 800000
#define NBX 168
#define NBY 480
#define NCK 8
#define NCE 8
#define NBINS (NBX * NBY)
#define YB_ROWS 30                 // y-bucket / tile row granularity
#define NYB 16
#define NBUCK (NYB * NBX)          // 2,688 buckets; id = yb*NBX + col
#define CAPB 536                   // worst bucket ~430 expected + 5sigma (clean since R8)
#define TC 4                       // tile columns per main block
#define NTX (NBX / TC)             // 42
#define NSCAN 8                    // buckets C0-2 .. C0+5 == one per wave
#define ACCSTRIDE 66               // floats per (col,row) cell group (64 + 2 pad)
#define BS 512                     // 8 waves = 8 buckets
#define MPT 8
#define FILL_BLOCKS 98             // 98*1024*8 = 802,816 >= NUM_FLOPS
#define S_INVSQRT2 0.7071067811865476f

// -------- workspace layout --------
// scale    : float [NBINS]        @ 0           (322.6 KB)
// cnt      : int   [NBUCK]        @ +NBINS      (10.8 KB)
// bin_of_f : int   [NUM_FLOPS]    @ +NBUCK      (3.2 MB)
// rec      : Rec12 [NBUCK*CAPB]                 (17.3 MB)   total 20.8 MB (fits since R8)

struct Rec12 { float cx, cy; int fke; };  // fke = (rowrel << 6) | ke, rowrel in [0,33]

// Branch-free erf, Abramowitz-Stegun 7.1.26 (max abs err 1.5e-7)
__device__ __forceinline__ float fast_erf(float x) {
    float ax = fabsf(x);
    float t = __builtin_amdgcn_rcpf(fmaf(0.3275911f, ax, 1.0f));
    float p = t * fmaf(t, fmaf(t, fmaf(t, fmaf(t, 1.061405429f, -1.453152027f),
                                       1.421413741f), -0.284496736f), 0.254829592f);
    float r = fmaf(-p, __expf(-ax * ax), 1.0f);
    return copysignf(r, x);
}

__global__ void __launch_bounds__(1024)
ff_fill(const float* __restrict__ pos,
        const float* __restrict__ nsx,
        const float* __restrict__ nsy,
        const int* __restrict__ fi,
        const int* __restrict__ cs,
        int* __restrict__ cnt,
        int* __restrict__ bin_of_f,
        Rec12* __restrict__ rec,
        float* __restrict__ out) {
    __shared__ int h[NBUCK];
    __shared__ int base[NBUCK];
    int tid = threadIdx.x;

    for (int g = blockIdx.x * 1024 + tid; g < NUM_NODES; g += FILL_BLOCKS * 1024)
        out[g] = 0.f;

    for (int j = tid; j < NBUCK; j += 1024) h[j] = 0;
    __syncthreads();

    float cx[MPT], cy[MPT];
    int fke[MPT], b1[MPT], r1[MPT], b2[MPT], r2[MPT];
    int f0 = blockIdx.x * (1024 * MPT);
#pragma unroll
    for (int m = 0; m < MPT; ++m) {
        int f = f0 + m * 1024 + tid;
        b1[m] = -1; b2[m] = -1;
        if (f < NUM_FLOPS) {
            int i = fi[f];
            float X = pos[i] + 0.5f * nsx[i];
            float Y = pos[NUM_NODES + i] + 0.5f * nsy[i];
            cx[m] = X; cy[m] = Y;
            int bx0 = (int)floorf(X); bx0 = bx0 < 0 ? 0 : (bx0 > NBX - 1 ? NBX - 1 : bx0);
            int by0 = (int)floorf(Y); by0 = by0 < 0 ? 0 : (by0 > NBY - 1 ? NBY - 1 : by0);
            int ke = cs[2 * f] * NCE + cs[2 * f + 1];
            int yb = by0 / YB_ROWS;
            int rlo = by0 - yb * YB_ROWS;
            fke[m] = ((rlo + 2) << 6) | ke;
            b1[m] = yb * NBX + bx0;
            bin_of_f[f] = bx0 * NBY + by0;
            r1[m] = atomicAdd(&h[b1[m]], 1);
            if (rlo <= 1 && yb > 0)             b2[m] = b1[m] - NBX;  // halo up
            else if (rlo >= 28 && yb < NYB - 1) b2[m] = b1[m] + NBX;  // halo down
            if (b2[m] >= 0) r2[m] = atomicAdd(&h[b2[m]], 1);
        }
    }
    __syncthreads();
    int off = (blockIdx.x * 911) % NBUCK;
    for (int j = tid; j < NBUCK; j += 1024) {
        int jj = j + off; if (jj >= NBUCK) jj -= NBUCK;
        base[jj] = h[jj] ? atomicAdd(&cnt[jj], h[jj]) : 0;
    }
    __syncthreads();
#pragma unroll
    for (int m = 0; m < MPT; ++m) {
        if (b1[m] >= 0) {
            Rec12 v; v.cx = cx[m]; v.cy = cy[m]; v.fke = fke[m];
            int s1 = base[b1[m]] + r1[m];
            if (s1 < CAPB) rec[(size_t)b1[m] * CAPB + s1] = v;
            if (b2[m] >= 0) {
                int rr = (b2[m] < b1[m]) ? ((fke[m] >> 6) & 63) + 30
                                         : ((fke[m] >> 6) & 63) - 30;
                Rec12 w; w.cx = cx[m]; w.cy = cy[m]; w.fke = (fke[m] & 63) | (rr << 6);
                int s2 = base[b2[m]] + r2[m];
                if (s2 < CAPB) rec[(size_t)b2[m] * CAPB + s2] = w;
            }
        }
    }
}

// One record visit: 5 x-edge erfs at ABSOLUTE tile-column edges C0..C0+4
// (constant indices -> no dynamic array select), 6 y-edge erfs; wave-uniform
// column validity (k uniform per wave). All control flow wave-uniform except
// the row guard + loop tail.
__device__ __forceinline__ void visit(float cx, float cyr, int fke, int k,
                                      float c0f, float* __restrict__ acc) {
    int ke = fke & 63;
    int rbase = ((fke >> 6) & 63) - 4;      // tile-relative first cell row
    float e0 = fast_erf((c0f + 0.f - cx) * S_INVSQRT2);
    float e1 = fast_erf((c0f + 1.f - cx) * S_INVSQRT2);
    float e2 = fast_erf((c0f + 2.f - cx) * S_INVSQRT2);
    float e3 = fast_erf((c0f + 3.f - cx) * S_INVSQRT2);
    float e4 = fast_erf((c0f + 4.f - cx) * S_INVSQRT2);
    float wx0 = 0.5f * (e1 - e0);
    float wx1 = 0.5f * (e2 - e1);
    float wx2 = 0.5f * (e3 - e2);
    float wx3 = 0.5f * (e4 - e3);
    float fy0 = (float)rbase - cyr;
    float ey0 = fast_erf(fy0 * S_INVSQRT2);
    float ey1 = fast_erf((fy0 + 1.f) * S_INVSQRT2);
    float ey2 = fast_erf((fy0 + 2.f) * S_INVSQRT2);
    float ey3 = fast_erf((fy0 + 3.f) * S_INVSQRT2);
    float ey4 = fast_erf((fy0 + 4.f) * S_INVSQRT2);
    float ey5 = fast_erf((fy0 + 5.f) * S_INVSQRT2);
    float wy0 = 0.5f * (ey1 - ey0);
    float wy1 = 0.5f * (ey2 - ey1);
    float wy2 = 0.5f * (ey3 - ey2);
    float wy3 = 0.5f * (ey4 - ey3);
    float wy4 = 0.5f * (ey5 - ey4);
#pragma unroll
    for (int cc = 0; cc < TC; ++cc) {
        if ((unsigned)(cc - k + 4) <= 4u) {          // wave-uniform branch
            float wx = (cc == 0) ? wx0 : (cc == 1) ? wx1 : (cc == 2) ? wx2 : wx3;
            float* ab = acc + (cc * YB_ROWS) * ACCSTRIDE + ke;
#pragma unroll
            for (int j = 0; j < 5; ++j) {
                int row = rbase + j;
                float wy = (j == 0) ? wy0 : (j == 1) ? wy1 : (j == 2) ? wy2
                           : (j == 3) ? wy3 : wy4;
                if ((unsigned)row < YB_ROWS)
                    atomicAdd(ab + row * ACCSTRIDE, wx * wy);
            }
        }
    }
}

// Block owns 4-col x 30-row x 64-ke LDS tile. Wave w scans bucket C0-2+w
// entirely: bucket id/count/column-offset all wave-uniform -> no waterfalls,
// no divergent bucket-find. 2-record interleave for MLP.
__global__ void __launch_bounds__(BS, 4)
ff_main(const int* __restrict__ cnt,
        const Rec12* __restrict__ rec,
        float* __restrict__ scale) {
    __shared__ float acc[TC * YB_ROWS * ACCSTRIDE];   // 31,680 B -> 2 blocks/CU
    int tid = threadIdx.x;
    int wave = tid >> 6, lane = tid & 63;
    int C0 = blockIdx.x * TC;
    int yb = blockIdx.y;
    int y0 = yb * YB_ROWS;

    for (int j = tid; j < TC * YB_ROWS * ACCSTRIDE; j += BS) acc[j] = 0.f;
    __syncthreads();

    int k = wave;                          // this wave's bucket: col C0-2+k
    int c = C0 - 2 + k;
    int n = 0;
    const Rec12* bp = rec;
    if ((unsigned)c < (unsigned)NBX) {
        n = cnt[yb * NBX + c];
        n = n < CAPB ? n : CAPB;
        bp = rec + (size_t)(yb * NBX + c) * CAPB;
    }
    float c0f = (float)C0;
    float y0f = (float)y0;

    for (int r = lane; r < n; r += 128) {
        Rec12 v0 = bp[r];
        int r1 = r + 64;
        bool h1 = r1 < n;
        Rec12 v1 = h1 ? bp[r1] : v0;
        visit(v0.cx, v0.cy - y0f, v0.fke, k, c0f, acc);
        if (h1) visit(v1.cx, v1.cy - y0f, v1.fke, k, c0f, acc);
    }
    __syncthreads();

    // fused quantization reduce: threads 0..119 each own one (col,row) bin
    if (tid < TC * YB_ROWS) {
        int cc = tid / YB_ROWS, r = tid - cc * YB_ROWS;
        const float* p = acc + (cc * YB_ROWS + r) * ACCSTRIDE;
        float tot2 = 0.f, halves = 0.f;
#pragma unroll
        for (int ck = 0; ck < NCK; ++ck) {
            float q = 0.f;
#pragma unroll
            for (int e = 0; e < NCE; ++e) {
                float d = p[ck * NCE + e];
                tot2 += d;
                q += ceilf(d * 0.25f);
            }
            halves += ceilf(0.5f * q);
        }
        float slices = ceilf(0.5f * halves);
        scale[(C0 + cc) * NBY + y0 + r] = (tot2 > 0.f) ? (slices / fmaxf(tot2, 1e-12f)) : 0.f;
    }
}

__global__ void ff_gather(const int* __restrict__ fi,
                          const int* __restrict__ bin_of_f,
                          const float* __restrict__ scale,
                          float* __restrict__ out) {
    int f = blockIdx.x * blockDim.x + threadIdx.x;
    if (f >= NUM_FLOPS) return;
    out[fi[f]] = scale[bin_of_f[f]];
}

extern "C" void kernel_launch(void* const* d_in, const int* in_sizes, int n_in,
                              void* d_out, int out_size, void* d_ws, size_t ws_size,
                              hipStream_t stream) {
    const float* pos = (const float*)d_in[0];
    const float* nsx = (const float*)d_in[1];
    const float* nsy = (const float*)d_in[2];
    const int*   fi  = (const int*)d_in[3];
    const int*   cs  = (const int*)d_in[4];
    float* out = (float*)d_out;

    float* scale    = (float*)d_ws;
    int*   cnt      = (int*)(scale + NBINS);
    int*   bin_of_f = cnt + NBUCK;
    Rec12* rec      = (Rec12*)(bin_of_f + NUM_FLOPS);

    hipMemsetAsync(cnt, 0, NBUCK * sizeof(int), stream);

    ff_fill<<<FILL_BLOCKS, 1024, 0, stream>>>(pos, nsx, nsy, fi, cs,
                                              cnt, bin_of_f, rec, out);
    ff_main<<<dim3(NTX, NYB), BS, 0, stream>>>(cnt, rec, scale);
    ff_gather<<<(NUM_FLOPS + 255) / 256, 256, 0, stream>>>(fi, bin_of_f, scale, out);
}